// Round 2
// baseline (43.781 us; speedup 1.0000x reference)
//
#include <hip/hip_runtime.h>
#include <math.h>

typedef __attribute__((ext_vector_type(8))) short short8;
typedef __attribute__((ext_vector_type(4))) float f32x4;

__device__ __forceinline__ unsigned short f2bf(float x) {
    unsigned u = __float_as_uint(x);
    u += 0x7FFFu + ((u >> 16) & 1u);   // round-to-nearest-even
    return (unsigned short)(u >> 16);
}

// Kernel 1: W2 (256x256 f32, row-major k x col) -> bf16 MFMA B-fragment order,
// and zero the pooled accumulator (512x256 f32).
// frag id f = (kt*16 + ct)*64 + l ; element j = W2[kt*32 + (l>>4)*8 + j][ct*16 + (l&15)]
__global__ __launch_bounds__(256) void prep_kernel(const float* __restrict__ W2,
                                                   unsigned short* __restrict__ W2p,
                                                   float* __restrict__ pooled) {
    int gid = blockIdx.x * 256 + threadIdx.x;      // 0..131071
    pooled[gid] = 0.f;
    if (gid < 8192) {
        int l = gid & 63;
        int ct = (gid >> 6) & 15;
        int kt = gid >> 10;
        int col  = ct * 16 + (l & 15);
        int krow = kt * 32 + ((l >> 4) * 8);
        short8 v;
#pragma unroll
        for (int j = 0; j < 8; ++j) v[j] = (short)f2bf(W2[(krow + j) * 256 + col]);
        *reinterpret_cast<short8*>(W2p + (size_t)gid * 8) = v;
    }
}

// Kernel 2: per (batch, row-octant) block. 32 rows x 256 cols of h2, masked-pooled
// into pooled[b][col] via atomicAdd.
__global__ __launch_bounds__(256, 4) void actor_kernel(
    const float* __restrict__ obs,  const float* __restrict__ obst,
    const float* __restrict__ W1,   const float* __restrict__ b1,
    const float* __restrict__ b2,   const unsigned short* __restrict__ W2p,
    float* __restrict__ pooled)
{
    __shared__ __align__(16) short sA[2][2048];   // 2 x (32 rows x 64 k) bf16, swizzled (8 KB)
    __shared__ __align__(16) float sW1oT[256][4];
    __shared__ float sVehW1[256];

    const int bq = blockIdx.x;
    const int b  = bq >> 3;
    const int q  = bq & 7;          // row octant: rows [q*32, q*32+32)
    const int t  = threadIdx.x;
    const int l  = t & 63;
    const int w  = t >> 6;          // wave = col group: cols [w*64, w*64+64)

    // ---- stage: W1 obstacle rows (transposed) + per-batch veh@W1[:15]+b1 ----
    {
        float4 v;
        v.x = W1[15 * 256 + t];
        v.y = W1[16 * 256 + t];
        v.z = W1[17 * 256 + t];
        v.w = W1[18 * 256 + t];
        *reinterpret_cast<float4*>(&sW1oT[t][0]) = v;
        float a = b1[t];
#pragma unroll
        for (int i = 0; i < 15; ++i) a = fmaf(obs[b * 15 + i], W1[i * 256 + t], a);
        sVehW1[t] = a;
    }

    const int n_thr = t & 31;                 // local row this thread produces
    const int jh    = (t >> 5) * 8;           // k sub-block within 64-k slice
    const float o0 = obst[b * 1280 + 0 * 256 + q * 32 + n_thr];
    const float o1 = obst[b * 1280 + 1 * 256 + q * 32 + n_thr];
    const float o2 = obst[b * 1280 + 2 * 256 + q * 32 + n_thr];
    const float o3 = obst[b * 1280 + 3 * 256 + q * 32 + n_thr];
    __syncthreads();

    // layer-1 slice: h1[n][s*64 .. +64) -> bf16 into sA[buf], 128-B rows, XOR-swizzled
    auto computeSlice = [&](int s, int buf) {
        short8 hv;
#pragma unroll
        for (int u = 0; u < 8; ++u) {
            int j = s * 64 + jh + u;
            float4 wv = *reinterpret_cast<const float4*>(&sW1oT[j][0]);
            float v = sVehW1[j];
            v = fmaf(o0, wv.x, v);
            v = fmaf(o1, wv.y, v);
            v = fmaf(o2, wv.z, v);
            v = fmaf(o3, wv.w, v);
            v = fmaxf(v, 0.f);
            hv[u] = (short)f2bf(v);
        }
        unsigned off = ((unsigned)(jh * 2)) ^ ((unsigned)((n_thr & 7) << 4));
        *reinterpret_cast<short8*>((char*)&sA[buf][0] + n_thr * 128 + off) = hv;
    };

    f32x4 acc[2][4];
#pragma unroll
    for (int m = 0; m < 2; ++m)
#pragma unroll
        for (int c = 0; c < 4; ++c) acc[m][c] = (f32x4){0.f, 0.f, 0.f, 0.f};

    computeSlice(0, 0);
    __syncthreads();

    for (int s = 0; s < 4; ++s) {
        int buf = s & 1;
        if (s < 3) computeSlice(s + 1, buf ^ 1);   // VALU work overlaps MFMA pipe
#pragma unroll
        for (int kk = 0; kk < 2; ++kk) {
            int kt = s * 2 + kk;
            short8 bfr[4];
#pragma unroll
            for (int c = 0; c < 4; ++c)
                bfr[c] = *reinterpret_cast<const short8*>(
                    W2p + (size_t)(((kt * 16 + w * 4 + c) * 64 + l) * 8));
#pragma unroll
            for (int m = 0; m < 2; ++m) {
                int n = m * 16 + (l & 15);
                unsigned off = (unsigned)(n * 128) +
                               (((unsigned)(kk * 64 + ((l >> 4) * 16))) ^ ((unsigned)((n & 7) << 4)));
                short8 afr = *reinterpret_cast<const short8*>((const char*)&sA[buf][0] + off);
#pragma unroll
                for (int c = 0; c < 4; ++c)
                    acc[m][c] = __builtin_amdgcn_mfma_f32_16x16x32_bf16(afr, bfr[c], acc[m][c], 0, 0, 0);
            }
        }
        if (s < 3) __syncthreads();
    }

    // ---- masked pooling of this block's 32 rows ----
    const float* maskp = obst + b * 1280 + 1024 + q * 32;
#pragma unroll
    for (int c = 0; c < 4; ++c) {
        int col = w * 64 + c * 16 + (l & 15);
        float bb = b2[col];
        float p = 0.f;
#pragma unroll
        for (int m = 0; m < 2; ++m) {
            int r0 = m * 16 + ((l >> 4) * 4);
            float4 M = *reinterpret_cast<const float4*>(maskp + r0);
            f32x4 v = acc[m][c];
            p = fmaf(M.x, fmaxf(v[0] + bb, 0.f), p);
            p = fmaf(M.y, fmaxf(v[1] + bb, 0.f), p);
            p = fmaf(M.z, fmaxf(v[2] + bb, 0.f), p);
            p = fmaf(M.w, fmaxf(v[3] + bb, 0.f), p);
        }
        p += __shfl_xor(p, 16);
        p += __shfl_xor(p, 32);
        if (l < 16) atomicAdd(&pooled[b * 256 + col], p);
    }
}

// Kernel 3: Gaussian head, one wave per batch.
__global__ __launch_bounds__(64) void head_kernel(
    const float* __restrict__ pooled, const float* __restrict__ eps,
    const float* __restrict__ muW,    const float* __restrict__ mub,
    const float* __restrict__ lsW,    const float* __restrict__ lsb,
    float* __restrict__ out)
{
    const int b = blockIdx.x;
    const int l = threadIdx.x;
    float m0 = 0.f, m1 = 0.f, s0 = 0.f, s1 = 0.f;
#pragma unroll
    for (int hh = 0; hh < 4; ++hh) {
        int h = l + hh * 64;
        float p = pooled[b * 256 + h];
        m0 = fmaf(p, muW[h * 2 + 0], m0);
        m1 = fmaf(p, muW[h * 2 + 1], m1);
        s0 = fmaf(p, lsW[h * 2 + 0], s0);
        s1 = fmaf(p, lsW[h * 2 + 1], s1);
    }
#pragma unroll
    for (int off = 32; off > 0; off >>= 1) {
        m0 += __shfl_xor(m0, off);
        m1 += __shfl_xor(m1, off);
        s0 += __shfl_xor(s0, off);
        s1 += __shfl_xor(s1, off);
    }
    if (l == 0) {
        float mu0 = m0 + mub[0], mu1 = m1 + mub[1];
        float ls0 = fminf(fmaxf(s0 + lsb[0], -20.f), 2.f);
        float ls1 = fminf(fmaxf(s1 + lsb[1], -20.f), 2.f);
        float e0 = eps[b * 2 + 0], e1 = eps[b * 2 + 1];
        float a0 = fmaf(expf(ls0), e0, mu0);
        float a1 = fmaf(expf(ls1), e1, mu1);
        float logp = -0.5f * (e0 * e0 + e1 * e1) - (ls0 + ls1) - 1.8378770664093453f;
        float x0 = -2.f * a0, x1 = -2.f * a1;
        float sp0 = fmaxf(x0, 0.f) + log1pf(expf(-fabsf(x0)));
        float sp1 = fmaxf(x1, 0.f) + log1pf(expf(-fabsf(x1)));
        logp -= 2.f * (0.6931471805599453f - a0 - sp0);
        logp -= 2.f * (0.6931471805599453f - a1 - sp1);
        out[b * 2 + 0] = tanhf(a0);
        out[b * 2 + 1] = tanhf(a1);
        out[1024 + b] = logp;
    }
}

extern "C" void kernel_launch(void* const* d_in, const int* in_sizes, int n_in,
                              void* d_out, int out_size, void* d_ws, size_t ws_size,
                              hipStream_t stream) {
    const float* obs  = (const float*)d_in[0];
    const float* obst = (const float*)d_in[1];
    const float* eps  = (const float*)d_in[2];
    const float* W1   = (const float*)d_in[3];
    const float* b1   = (const float*)d_in[4];
    const float* W2   = (const float*)d_in[5];
    const float* b2   = (const float*)d_in[6];
    const float* muW  = (const float*)d_in[7];
    const float* mub  = (const float*)d_in[8];
    const float* lsW  = (const float*)d_in[9];
    const float* lsb  = (const float*)d_in[10];
    float* out = (float*)d_out;

    unsigned short* W2p = (unsigned short*)d_ws;                   // 128 KB
    float* pooled = (float*)((char*)d_ws + 131072);                // 512 KB

    prep_kernel<<<512, 256, 0, stream>>>(W2, W2p, pooled);
    actor_kernel<<<4096, 256, 0, stream>>>(obs, obst, W1, b1, b2, W2p, pooled);
    head_kernel<<<512, 64, 0, stream>>>(pooled, eps, muW, mub, lsW, lsb, out);
}